// Round 1
// baseline (327.034 us; speedup 1.0000x reference)
//
#include <hip/hip_runtime.h>
#include <hip/hip_bf16.h>

typedef __attribute__((ext_vector_type(8))) short short8;
typedef __attribute__((ext_vector_type(4))) float floatx4;

#define C_DIM 256
#define BM 128
#define BN 128
#define BK 128
#define LDS_PAD 8
#define NCE_T_INV 14.285714285714286f

// ---------------------------------------------------------------------------
// Kernel 1: gather downsampled labels.
// lab[p] = seg[(c0*H/crw), (c1*W/crh), (c2*D/crd)]  for seg of shape HxWxD
// ---------------------------------------------------------------------------
__global__ void labels_kernel(const int* __restrict__ seg,
                              const int* __restrict__ coords,
                              const int* __restrict__ crw,
                              const int* __restrict__ crh,
                              const int* __restrict__ crd,
                              int* __restrict__ lab, int N, int H, int W, int D) {
    int p = blockIdx.x * blockDim.x + threadIdx.x;
    if (p >= N) return;
    int c0 = coords[3 * p + 0];
    int c1 = coords[3 * p + 1];
    int c2 = coords[3 * p + 2];
    int i0 = (c0 * H) / crw[0];
    int i1 = (c1 * W) / crh[0];
    int i2 = (c2 * D) / crd[0];
    lab[p] = seg[(i0 * W + i1) * D + i2];
}

// ---------------------------------------------------------------------------
// Kernel 2: L2-normalize each row of f (M x 256 fp32) -> bf16 bits in g.
// One wave (64 threads) per row; each lane handles 4 consecutive floats.
// ---------------------------------------------------------------------------
__global__ void norm_kernel(const float* __restrict__ f,
                            unsigned short* __restrict__ g) {
    int row = blockIdx.x;
    int lane = threadIdx.x;  // 0..63
    const float4 v = ((const float4*)(f + (size_t)row * C_DIM))[lane];
    float ss = v.x * v.x + v.y * v.y + v.z * v.z + v.w * v.w;
#pragma unroll
    for (int off = 32; off; off >>= 1) ss += __shfl_xor(ss, off, 64);
    float inv = 1.0f / sqrtf(ss);

    ushort4 o;
    __hip_bfloat16 b0 = __float2bfloat16(v.x * inv);
    __hip_bfloat16 b1 = __float2bfloat16(v.y * inv);
    __hip_bfloat16 b2 = __float2bfloat16(v.z * inv);
    __hip_bfloat16 b3 = __float2bfloat16(v.w * inv);
    o.x = __builtin_bit_cast(unsigned short, b0);
    o.y = __builtin_bit_cast(unsigned short, b1);
    o.z = __builtin_bit_cast(unsigned short, b2);
    o.w = __builtin_bit_cast(unsigned short, b3);
    ((ushort4*)g)[(size_t)row * (C_DIM / 4) + lane] = o;
}

// ---------------------------------------------------------------------------
// Kernel 3: zero the per-row accumulators (ws is poisoned 0xAA each call).
// ---------------------------------------------------------------------------
__global__ void zero_kernel(float* __restrict__ p, int n) {
    int i = blockIdx.x * blockDim.x + threadIdx.x;
    if (i < n) p[i] = 0.0f;
}

// ---------------------------------------------------------------------------
// Kernel 4: fused Gram-tile kernel. One block = 128x128 output tile of
// sim = G @ G^T (G: M x 256 bf16, rows pre-normalized). Epilogue computes
// per-row partial sums of exp((sim-1)/T), pos*(sim-1)/T, pos-count and
// atomically accumulates into rs_exp / rs_num / rs_cnt.
// 256 threads = 4 waves in 2x2, each wave computes 64x64 via 16x16x32 MFMA.
// ---------------------------------------------------------------------------
__global__ __launch_bounds__(256, 2) void
gram_kernel(const unsigned short* __restrict__ G,
            const int* __restrict__ lab,
            float* __restrict__ rs_exp,
            float* __restrict__ rs_num,
            float* __restrict__ rs_cnt,
            int labmask) {
    __shared__ unsigned short As[BM][BK + LDS_PAD];
    __shared__ unsigned short Bs[BN][BK + LDS_PAD];

    const int tileN = blockIdx.x;
    const int tileM = blockIdx.y;
    const int tid = threadIdx.x;
    const int lane = tid & 63;
    const int wave = tid >> 6;          // 0..3
    const int waveM = wave >> 1;        // 0..1
    const int waveN = wave & 1;         // 0..1
    const int cc = lane & 15;           // col within 16x16 frag
    const int cq = lane >> 4;           // quad -> row group of 4

    const int rowA0 = tileM * BM;
    const int rowB0 = tileN * BN;

    floatx4 acc[4][4] = {};

    for (int kk = 0; kk < C_DIM; kk += BK) {
        // ---- stage A and B tiles (128 x 128 bf16 each) ----
#pragma unroll
        for (int t = 0; t < 8; ++t) {
            int vi = tid + t * 256;       // 0..2047
            int row = vi >> 4;            // 0..127
            int cv = vi & 15;             // 0..15 (x8 elems)
            *(uint4*)&As[row][cv * 8] =
                *(const uint4*)&G[(size_t)(rowA0 + row) * C_DIM + kk + cv * 8];
            *(uint4*)&Bs[row][cv * 8] =
                *(const uint4*)&G[(size_t)(rowB0 + row) * C_DIM + kk + cv * 8];
        }
        __syncthreads();

        // ---- MFMA over this K-slab ----
#pragma unroll
        for (int ks = 0; ks < BK; ks += 32) {
            short8 af[4], bfr[4];
#pragma unroll
            for (int mi = 0; mi < 4; ++mi)
                af[mi] = *(const short8*)&As[waveM * 64 + mi * 16 + cc][ks + cq * 8];
#pragma unroll
            for (int ni = 0; ni < 4; ++ni)
                bfr[ni] = *(const short8*)&Bs[waveN * 64 + ni * 16 + cc][ks + cq * 8];
#pragma unroll
            for (int mi = 0; mi < 4; ++mi)
#pragma unroll
                for (int ni = 0; ni < 4; ++ni)
                    acc[mi][ni] = __builtin_amdgcn_mfma_f32_16x16x32_bf16(
                        af[mi], bfr[ni], acc[mi][ni], 0, 0, 0);
        }
        __syncthreads();
    }

    // ---- epilogue: exp / mask / per-row reduce / atomic accumulate ----
    const int rowbase = rowA0 + waveM * 64;
    const int colbase = rowB0 + waveN * 64;

    int col_lab[4];
#pragma unroll
    for (int ni = 0; ni < 4; ++ni)
        col_lab[ni] = lab[(colbase + ni * 16 + cc) & labmask];

#pragma unroll
    for (int mi = 0; mi < 4; ++mi) {
#pragma unroll
        for (int r = 0; r < 4; ++r) {
            const int row = rowbase + mi * 16 + cq * 4 + r;
            const int rlab = lab[row & labmask];
            float se = 0.0f, nu = 0.0f, ct = 0.0f;
#pragma unroll
            for (int ni = 0; ni < 4; ++ni) {
                const int col = colbase + ni * 16 + cc;
                const float ls = (acc[mi][ni][r] - 1.0f) * NCE_T_INV;
                const bool diag = (col == row);
                se += diag ? 0.0f : __expf(ls);
                const bool pos = (!diag) && (col_lab[ni] == rlab);
                nu += pos ? ls : 0.0f;
                ct += pos ? 1.0f : 0.0f;
            }
#pragma unroll
            for (int off = 1; off < 16; off <<= 1) {
                se += __shfl_xor(se, off, 64);
                nu += __shfl_xor(nu, off, 64);
                ct += __shfl_xor(ct, off, 64);
            }
            if (cc == 0) {
                atomicAdd(&rs_exp[row], se);
                atomicAdd(&rs_num[row], nu);
                atomicAdd(&rs_cnt[row], ct);
            }
        }
    }
}

// ---------------------------------------------------------------------------
// Kernel 5: finalize. loss = -mean_i( num_i/cnt_i - log(exp_i) )
// ---------------------------------------------------------------------------
__global__ void finalize_kernel(const float* __restrict__ rs_exp,
                                const float* __restrict__ rs_num,
                                const float* __restrict__ rs_cnt,
                                float* __restrict__ out, int M) {
    __shared__ float red[256];
    float s = 0.0f;
    for (int i = threadIdx.x; i < M; i += 256)
        s += rs_num[i] / rs_cnt[i] - logf(rs_exp[i]);
    red[threadIdx.x] = s;
    __syncthreads();
    for (int k = 128; k; k >>= 1) {
        if (threadIdx.x < k) red[threadIdx.x] += red[threadIdx.x + k];
        __syncthreads();
    }
    if (threadIdx.x == 0) out[0] = -red[0] / (float)M;
}

extern "C" void kernel_launch(void* const* d_in, const int* in_sizes, int n_in,
                              void* d_out, int out_size, void* d_ws, size_t ws_size,
                              hipStream_t stream) {
    const float* features = (const float*)d_in[0];
    const int* labels_seg = (const int*)d_in[1];
    const int* labels_coords = (const int*)d_in[2];
    const int* crw = (const int*)d_in[3];
    const int* crh = (const int*)d_in[4];
    const int* crd = (const int*)d_in[5];
    float* out = (float*)d_out;

    const int N = in_sizes[2] / 3;            // 4096 patches
    const int M = in_sizes[0] / C_DIM;        // 8192 rows (ntps * N)
    const int H = 128, W = 128, D = 128;      // labels_seg spatial dims

    // workspace layout
    char* ws = (char*)d_ws;
    unsigned short* g = (unsigned short*)ws;                        // M*256 bf16
    int* lab = (int*)(ws + (size_t)M * C_DIM * 2);                  // N ints
    float* rs = (float*)(ws + (size_t)M * C_DIM * 2 + (size_t)N * 4);
    float* rs_exp = rs;
    float* rs_num = rs + M;
    float* rs_cnt = rs + 2 * M;

    labels_kernel<<<(N + 255) / 256, 256, 0, stream>>>(
        labels_seg, labels_coords, crw, crh, crd, lab, N, H, W, D);

    norm_kernel<<<M, 64, 0, stream>>>(features, g);

    zero_kernel<<<(3 * M + 255) / 256, 256, 0, stream>>>(rs, 3 * M);

    dim3 grid(M / BN, M / BM);
    gram_kernel<<<grid, 256, 0, stream>>>(g, lab, rs_exp, rs_num, rs_cnt, N - 1);

    finalize_kernel<<<1, 256, 0, stream>>>(rs_exp, rs_num, rs_cnt, out, M);
}